// Round 5
// baseline (162.383 us; speedup 1.0000x reference)
//
#include <hip/hip_runtime.h>
#include <math.h>

// B=8, N=1024, D=128.  kv[b,n,512] = [k_mu | v_mu | k_sigma | v_sigma]
// 2-kernel plan:
//  1) prepass: split fp32 -> (hi,lo) bf16, stored in MFMA-fragment order:
//     frag[side][b][tile16][kc][arr][1KB chunk], chunk = 64 lanes x 16B.
//     Also zeroes acc+counters in ws and seeds out log-prob slots (LPCONST).
//  2) gemm (js=8, 1024 blocks, 4 waves): no LDS staging / no barriers in the
//     K-loop; 3-product split-bf16 MFMA 16x16x32; geometric epilogue folds S
//     into per-i sums; DPP reduces the 16 j-lanes; cross-wave LDS combine;
//     atomicAdd into acc[b][i][6]. Completion counter per (b,itb): the last
//     of the 8 js-blocks runs the tanh-normal tail for its 64 rows and
//     atomicAdds the per-wave log_prob into out. No third kernel.

#define NTOK 1024
#define LPCONST 14147.0828114f   // -3072*ln(0.01)

typedef __bf16 bf16x8 __attribute__((ext_vector_type(8)));
typedef float f32x4 __attribute__((ext_vector_type(4)));
#define MFMA(a, b, c) __builtin_amdgcn_mfma_f32_16x16x32_bf16(a, b, c, 0, 0, 0)

__device__ __forceinline__ void split1(float x, unsigned short& h, unsigned short& l) {
    unsigned u = __float_as_uint(x);
    unsigned hb = (u + 0x8000u) >> 16;
    float hf = __uint_as_float(hb << 16);
    unsigned lb = (__float_as_uint(x - hf) + 0x8000u) >> 16;
    h = (unsigned short)hb;
    l = (unsigned short)lb;
}

template <int CTRL>
__device__ __forceinline__ float dpp_add(float v) {
    int y = __builtin_amdgcn_update_dpp(0, __float_as_int(v), CTRL, 0xf, 0xf, true);
    return v + __int_as_float(y);
}
__device__ __forceinline__ float red16(float v) {
    v = dpp_add<0xB1>(v);    // xor1 within quad
    v = dpp_add<0x4E>(v);    // xor2 within quad
    v = dpp_add<0x141>(v);   // row_half_mirror
    v = dpp_add<0x140>(v);   // row_mirror
    return v;
}

__device__ __forceinline__ float softplusf(float z) {
    return z > 20.f ? z : log1pf(expf(z));
}

// ---------------- prepass ----------------
__global__ __launch_bounds__(256) void prepass_kernel(
    const float* __restrict__ kv, unsigned short* __restrict__ frag,
    float* __restrict__ acc_ws, unsigned int* __restrict__ counters,
    float* __restrict__ out)
{
    const int t = blockIdx.x * 256 + threadIdx.x;   // 0..262143

    // zero the accumulators / counters, seed log-prob constants
    if (t < 8 * NTOK * 6) acc_ws[t] = 0.f;
    if (t < 128) counters[t] = 0u;
    if (t < 8) out[8 * NTOK * 3 + t] = LPCONST;

    const int lane = t & 63;
    const int kc   = (t >> 6) & 3;
    const int tile = (t >> 8) & 63;
    const int b    = (t >> 14) & 7;
    const int side = t >> 17;

    const int row = tile * 16 + (lane & 15);
    const int kof = kc * 32 + (lane >> 4) * 8;
    const float* gp = kv + ((size_t)b * NTOK + row) * 512 + side * 128 + kof;
    const float4 m0 = *(const float4*)gp;
    const float4 m1 = *(const float4*)(gp + 4);
    const float4 s0 = *(const float4*)(gp + 256);
    const float4 s1 = *(const float4*)(gp + 260);

    unsigned short* cp = frag + (size_t)side * 4194304 +
                         ((size_t)(((b * 64 + tile) * 4 + kc) * 4) << 9) + lane * 8;
    ushort4 h0, l0, h1, l1;
    split1(m0.x, h0.x, l0.x); split1(m0.y, h0.y, l0.y);
    split1(m0.z, h0.z, l0.z); split1(m0.w, h0.w, l0.w);
    split1(m1.x, h1.x, l1.x); split1(m1.y, h1.y, l1.y);
    split1(m1.z, h1.z, l1.z); split1(m1.w, h1.w, l1.w);
    *(ushort4*)(cp +   0) = h0; *(ushort4*)(cp +   4) = h1;   // arr0 hi_mu
    *(ushort4*)(cp + 512) = l0; *(ushort4*)(cp + 516) = l1;   // arr1 lo_mu
    split1(s0.x, h0.x, l0.x); split1(s0.y, h0.y, l0.y);
    split1(s0.z, h0.z, l0.z); split1(s0.w, h0.w, l0.w);
    split1(s1.x, h1.x, l1.x); split1(s1.y, h1.y, l1.y);
    split1(s1.z, h1.z, l1.z); split1(s1.w, h1.w, l1.w);
    *(ushort4*)(cp + 1024) = h0; *(ushort4*)(cp + 1028) = h1; // arr2 hi_sg
    *(ushort4*)(cp + 1536) = l0; *(ushort4*)(cp + 1540) = l1; // arr3 lo_sg
}

// ---------------- gemm + fused tail ----------------
__global__ __launch_bounds__(256, 4) void actor_gemm_kernel(
    const unsigned short* __restrict__ frag, const float* __restrict__ pos,
    const float* __restrict__ eps, float* __restrict__ acc_ws,
    unsigned int* __restrict__ counters, float* __restrict__ out)
{
    const int t = threadIdx.x;
    const int w = t >> 6;
    const int lane = t & 63;
    const int q = lane >> 4;
    const int r16 = lane & 15;
    const int js = blockIdx.x;       // 0..7  (x fastest -> js == linear%8 -> XCD swizzle)
    const int itb = blockIdx.y;      // 0..15
    const int b = blockIdx.z;
    const int i0 = itb * 64;
    const int jb = js * 128;

    const unsigned short* fragA = frag;
    const unsigned short* fragB = frag + 4194304;
    const float* posb = pos + (size_t)b * NTOK * 3;

    const int atile0 = b * 64 + itb * 4;            // +ig
    const int btile0 = b * 64 + js * 8 + w * 2;     // +jg
    const int lofs = lane * 8;

    f32x4 accm[4][2], accs[4][2];
    #pragma unroll
    for (int ig = 0; ig < 4; ++ig)
        #pragma unroll
        for (int jg = 0; jg < 2; ++jg) {
            accm[ig][jg] = (f32x4){0.f, 0.f, 0.f, 0.f};
            accs[ig][jg] = (f32x4){0.f, 0.f, 0.f, 0.f};
        }

    #pragma unroll
    for (int kc = 0; kc < 4; ++kc) {
        bf16x8 Bhm[2], Blm[2], Bhs[2], Bls[2];
        #pragma unroll
        for (int jg = 0; jg < 2; ++jg) {
            const unsigned short* bp =
                fragB + (((size_t)(btile0 + jg) * 16 + kc * 4) << 9) + lofs;
            Bhm[jg] = *(const bf16x8*)(bp);
            Blm[jg] = *(const bf16x8*)(bp + 512);
            Bhs[jg] = *(const bf16x8*)(bp + 1024);
            Bls[jg] = *(const bf16x8*)(bp + 1536);
        }
        #pragma unroll
        for (int ig = 0; ig < 4; ++ig) {
            const unsigned short* ap =
                fragA + (((size_t)(atile0 + ig) * 16 + kc * 4) << 9) + lofs;
            const bf16x8 Ahm = *(const bf16x8*)(ap);
            const bf16x8 Alm = *(const bf16x8*)(ap + 512);
            const bf16x8 Ahs = *(const bf16x8*)(ap + 1024);
            const bf16x8 Als = *(const bf16x8*)(ap + 1536);
            #pragma unroll
            for (int jg = 0; jg < 2; ++jg) {
                accm[ig][jg] = MFMA(Ahm, Bhm[jg], accm[ig][jg]);
                accm[ig][jg] = MFMA(Ahm, Blm[jg], accm[ig][jg]);
                accm[ig][jg] = MFMA(Alm, Bhm[jg], accm[ig][jg]);
                accs[ig][jg] = MFMA(Ahs, Bhs[jg], accs[ig][jg]);
                accs[ig][jg] = MFMA(Ahs, Bls[jg], accs[ig][jg]);
                accs[ig][jg] = MFMA(Als, Bhs[jg], accs[ig][jg]);
            }
        }
    }

    // ---- geometric epilogue (per-ig so acc[ig] dies as am/al grows) ----
    float am[4][4][3] = {};
    float al[4][4][3] = {};
    float pj[2][3];
    #pragma unroll
    for (int jg = 0; jg < 2; ++jg) {
        const int j = jb + w * 32 + jg * 16 + r16;
        pj[jg][0] = posb[j * 3 + 0];
        pj[jg][1] = posb[j * 3 + 1];
        pj[jg][2] = posb[j * 3 + 2];
    }
    #pragma unroll
    for (int ig = 0; ig < 4; ++ig)
        #pragma unroll
        for (int reg = 0; reg < 4; ++reg) {
            const int i = i0 + ig * 16 + q * 4 + reg;
            const float pix = posb[i * 3 + 0];
            const float piy = posb[i * 3 + 1];
            const float piz = posb[i * 3 + 2];
            #pragma unroll
            for (int jg = 0; jg < 2; ++jg) {
                const float dx = pix - pj[jg][0];
                const float dy = piy - pj[jg][1];
                const float dz = piz - pj[jg][2];
                const float d2 = dx * dx + dy * dy + dz * dz;
                const float inv = d2 > 0.f ? rsqrtf(d2) : 0.f;
                const float wm = accm[ig][jg][reg] * inv;
                const float ws = accs[ig][jg][reg] * inv;
                am[ig][reg][0] = fmaf(dx, wm, am[ig][reg][0]);
                am[ig][reg][1] = fmaf(dy, wm, am[ig][reg][1]);
                am[ig][reg][2] = fmaf(dz, wm, am[ig][reg][2]);
                al[ig][reg][0] = fmaf(dx, ws, al[ig][reg][0]);
                al[ig][reg][1] = fmaf(dy, ws, al[ig][reg][1]);
                al[ig][reg][2] = fmaf(dz, ws, al[ig][reg][2]);
            }
        }

    // ---- DPP-reduce the 16 j-lanes ----
    #pragma unroll
    for (int ig = 0; ig < 4; ++ig)
        #pragma unroll
        for (int reg = 0; reg < 4; ++reg)
            #pragma unroll
            for (int c = 0; c < 3; ++c) {
                am[ig][reg][c] = red16(am[ig][reg][c]);
                al[ig][reg][c] = red16(al[ig][reg][c]);
            }

    // ---- cross-wave combine via LDS ----
    __shared__ float wacc[4 * 64 * 6];
    if (r16 == 0) {
        #pragma unroll
        for (int ig = 0; ig < 4; ++ig)
            #pragma unroll
            for (int reg = 0; reg < 4; ++reg) {
                const int row = ig * 16 + q * 4 + reg;
                float* p = wacc + (w * 64 + row) * 6;
                p[0] = am[ig][reg][0]; p[1] = am[ig][reg][1]; p[2] = am[ig][reg][2];
                p[3] = al[ig][reg][0]; p[4] = al[ig][reg][1]; p[5] = al[ig][reg][2];
            }
    }
    __syncthreads();
    for (int u = t; u < 384; u += 256) {
        const int row = u / 6, c = u - row * 6;
        const float v = wacc[row * 6 + c] + wacc[(64 + row) * 6 + c] +
                        wacc[(128 + row) * 6 + c] + wacc[(192 + row) * 6 + c];
        atomicAdd(&acc_ws[((size_t)b * NTOK + i0 + row) * 6 + c], v);
    }

    // ---- completion counter; last js-block for (b,itb) runs the tail ----
    __syncthreads();                 // drains vmcnt -> all atomics complete
    __shared__ int is_last;
    if (t == 0) {
        unsigned old = atomicAdd(&counters[b * 16 + itb], 1u);
        is_last = (old == 7u);
    }
    __syncthreads();
    if (is_last) {
        __threadfence();
        if (t < 64) {
            const int gi = b * NTOK + i0 + t;
            float* ap = acc_ws + (size_t)gi * 6;
            float vals[6];
            #pragma unroll
            for (int c = 0; c < 6; ++c) vals[c] = atomicAdd(ap + c, 0.f);  // coherent read
            float lp = 0.f;
            #pragma unroll
            for (int c = 0; c < 3; ++c) {
                const float als = fminf(fmaxf(vals[3 + c], -20.f), 2.f);
                const float sd = expf(als);
                const float e = eps[gi * 3 + c];
                const float pre = fmaf(sd, e, vals[c]);
                out[gi * 3 + c] = tanhf(pre) * 0.01f;
                const float t2 = 2.f * pre;
                lp += -0.5f * e * e - als - 2.3052328944f + softplusf(t2) + softplusf(-t2);
            }
            #pragma unroll
            for (int m = 1; m < 64; m <<= 1) lp += __shfl_xor(lp, m, 64);
            if (t == 0) atomicAdd(out + NTOK * 8 * 3 + b, lp);
        }
    }
}

extern "C" void kernel_launch(void* const* d_in, const int* in_sizes, int n_in,
                              void* d_out, int out_size, void* d_ws, size_t ws_size,
                              hipStream_t stream) {
    const float* kv = (const float*)d_in[0];
    const float* pos = (const float*)d_in[1];
    const float* eps = (const float*)d_in[2];
    float* out = (float*)d_out;
    float* acc_ws = (float*)d_ws;                                       // 786 KiB
    unsigned int* counters = (unsigned int*)((char*)d_ws + 786432);     // 512 B
    unsigned short* frag = (unsigned short*)((char*)d_ws + (2 << 20));  // 16 MiB

    prepass_kernel<<<dim3(1024), 256, 0, stream>>>(kv, frag, acc_ws, counters, out);
    actor_gemm_kernel<<<dim3(8, 16, 8), 256, 0, stream>>>(frag, pos, eps, acc_ws,
                                                          counters, out);
}

// Round 6
// 100.097 us; speedup vs baseline: 1.6222x; 1.6222x over previous
//
#include <hip/hip_runtime.h>
#include <math.h>

// B=8, N=1024, D=128.  kv[b,n,512] = [k_mu | v_mu | k_sigma | v_sigma]
// 3-kernel plan (R3 skeleton, single-product bf16):
//  1) prepass: round fp32 -> bf16, stored in MFMA-fragment order:
//     frag[side][b][tile16][kc][arr][512], chunk = 64 lanes x 8 bf16 (16B).
//     arr: 0=mu 1=sg.  side 0 = K (cols 0/256), side 1 = V (cols 128/384).
//  2) gemm (js=8, 1024 blocks, 4 waves, no LDS staging, no barriers in the
//     K-loop): plain bf16 MFMA 16x16x32 (error is accum-noise dominated,
//     verified absmax 4096 identical for fp32 and split-bf16 schemes);
//     geometric epilogue folds S into per-i action sums; DPP reduces the
//     16 j-lanes; cross-wave LDS combine; partial[js][b][i][6].
//  3) tail: 128 blocks x 64 thr; sums 8 js partials, tanh-normal math,
//     per-wave log_prob reduce + atomicAdd (LPCONST seeded by gemm).
// NOTE: no __launch_bounds__ min-waves arg anywhere — (256,4) forced a
// 64-VGPR clamp and 100+ MB of scratch spill in R5.

#define NTOK 1024
#define LPCONST 14147.0828114f   // -3072*ln(0.01)

typedef __bf16 bf16x8 __attribute__((ext_vector_type(8)));
typedef float f32x4 __attribute__((ext_vector_type(4)));
#define MFMA(a, b, c) __builtin_amdgcn_mfma_f32_16x16x32_bf16(a, b, c, 0, 0, 0)

__device__ __forceinline__ unsigned short to_bf16(float x) {
    return (unsigned short)((__float_as_uint(x) + 0x8000u) >> 16);
}

template <int CTRL>
__device__ __forceinline__ float dpp_add(float v) {
    int y = __builtin_amdgcn_update_dpp(0, __float_as_int(v), CTRL, 0xf, 0xf, true);
    return v + __int_as_float(y);
}
__device__ __forceinline__ float red16(float v) {
    v = dpp_add<0xB1>(v);    // xor1 within quad
    v = dpp_add<0x4E>(v);    // xor2 within quad
    v = dpp_add<0x141>(v);   // row_half_mirror
    v = dpp_add<0x140>(v);   // row_mirror
    return v;
}

// ---------------- prepass ----------------
__global__ __launch_bounds__(256) void prepass_kernel(
    const float* __restrict__ kv, unsigned short* __restrict__ frag)
{
    const int t = blockIdx.x * 256 + threadIdx.x;   // 0..262143
    const int lane = t & 63;
    const int kc   = (t >> 6) & 3;
    const int tile = (t >> 8) & 63;
    const int b    = (t >> 14) & 7;
    const int side = t >> 17;

    const int row = tile * 16 + (lane & 15);
    const int kof = kc * 32 + (lane >> 4) * 8;
    const float* gp = kv + ((size_t)b * NTOK + row) * 512 + side * 128 + kof;
    const float4 m0 = *(const float4*)gp;
    const float4 m1 = *(const float4*)(gp + 4);
    const float4 s0 = *(const float4*)(gp + 256);
    const float4 s1 = *(const float4*)(gp + 260);

    // chunk = ((b*64+tile)*4 + kc)*2 + arr ; 512 ushorts per chunk
    unsigned short* cp = frag + (size_t)side * 2097152 +
                         ((size_t)(((b * 64 + tile) * 4 + kc) * 2) << 9) + lane * 8;
    ushort4 h0, h1;
    h0.x = to_bf16(m0.x); h0.y = to_bf16(m0.y); h0.z = to_bf16(m0.z); h0.w = to_bf16(m0.w);
    h1.x = to_bf16(m1.x); h1.y = to_bf16(m1.y); h1.z = to_bf16(m1.z); h1.w = to_bf16(m1.w);
    *(ushort4*)(cp + 0) = h0; *(ushort4*)(cp + 4) = h1;       // arr0 mu
    h0.x = to_bf16(s0.x); h0.y = to_bf16(s0.y); h0.z = to_bf16(s0.z); h0.w = to_bf16(s0.w);
    h1.x = to_bf16(s1.x); h1.y = to_bf16(s1.y); h1.z = to_bf16(s1.z); h1.w = to_bf16(s1.w);
    *(ushort4*)(cp + 512) = h0; *(ushort4*)(cp + 516) = h1;   // arr1 sg
}

// ---------------- gemm ----------------
__global__ __launch_bounds__(256) void actor_gemm_kernel(
    const unsigned short* __restrict__ frag, const float* __restrict__ pos,
    float* __restrict__ partial, float* __restrict__ out)
{
    const int t = threadIdx.x;
    const int w = t >> 6;
    const int lane = t & 63;
    const int q = lane >> 4;
    const int r16 = lane & 15;
    const int js = blockIdx.x;       // 0..7
    const int itb = blockIdx.y;      // 0..15
    const int b = blockIdx.z;
    const int i0 = itb * 64;
    const int jb = js * 128;

    const unsigned short* fragA = frag;
    const unsigned short* fragB = frag + 2097152;
    const float* posb = pos + (size_t)b * NTOK * 3;

    const int atile0 = b * 64 + itb * 4;            // +ig
    const int btile0 = b * 64 + js * 8 + w * 2;     // +jg
    const int lofs = lane * 8;

    f32x4 accm[4][2], accs[4][2];
    #pragma unroll
    for (int ig = 0; ig < 4; ++ig)
        #pragma unroll
        for (int jg = 0; jg < 2; ++jg) {
            accm[ig][jg] = (f32x4){0.f, 0.f, 0.f, 0.f};
            accs[ig][jg] = (f32x4){0.f, 0.f, 0.f, 0.f};
        }

    #pragma unroll
    for (int kc = 0; kc < 4; ++kc) {
        bf16x8 Bm[2], Bs[2];
        #pragma unroll
        for (int jg = 0; jg < 2; ++jg) {
            const unsigned short* bp =
                fragB + (((size_t)(btile0 + jg) * 8 + kc * 2) << 9) + lofs;
            Bm[jg] = *(const bf16x8*)(bp);
            Bs[jg] = *(const bf16x8*)(bp + 512);
        }
        #pragma unroll
        for (int ig = 0; ig < 4; ++ig) {
            const unsigned short* ap =
                fragA + (((size_t)(atile0 + ig) * 8 + kc * 2) << 9) + lofs;
            const bf16x8 Am = *(const bf16x8*)(ap);
            const bf16x8 As = *(const bf16x8*)(ap + 512);
            #pragma unroll
            for (int jg = 0; jg < 2; ++jg) {
                accm[ig][jg] = MFMA(Am, Bm[jg], accm[ig][jg]);
                accs[ig][jg] = MFMA(As, Bs[jg], accs[ig][jg]);
            }
        }
    }

    // ---- geometric epilogue ----
    float am[4][4][3] = {};
    float al[4][4][3] = {};
    float pj[2][3];
    #pragma unroll
    for (int jg = 0; jg < 2; ++jg) {
        const int j = jb + w * 32 + jg * 16 + r16;
        pj[jg][0] = posb[j * 3 + 0];
        pj[jg][1] = posb[j * 3 + 1];
        pj[jg][2] = posb[j * 3 + 2];
    }
    #pragma unroll
    for (int ig = 0; ig < 4; ++ig)
        #pragma unroll
        for (int reg = 0; reg < 4; ++reg) {
            const int i = i0 + ig * 16 + q * 4 + reg;
            const float pix = posb[i * 3 + 0];
            const float piy = posb[i * 3 + 1];
            const float piz = posb[i * 3 + 2];
            #pragma unroll
            for (int jg = 0; jg < 2; ++jg) {
                const float dx = pix - pj[jg][0];
                const float dy = piy - pj[jg][1];
                const float dz = piz - pj[jg][2];
                const float d2 = dx * dx + dy * dy + dz * dz;
                const float inv = d2 > 0.f ? rsqrtf(d2) : 0.f;
                const float wm = accm[ig][jg][reg] * inv;
                const float ws = accs[ig][jg][reg] * inv;
                am[ig][reg][0] = fmaf(dx, wm, am[ig][reg][0]);
                am[ig][reg][1] = fmaf(dy, wm, am[ig][reg][1]);
                am[ig][reg][2] = fmaf(dz, wm, am[ig][reg][2]);
                al[ig][reg][0] = fmaf(dx, ws, al[ig][reg][0]);
                al[ig][reg][1] = fmaf(dy, ws, al[ig][reg][1]);
                al[ig][reg][2] = fmaf(dz, ws, al[ig][reg][2]);
            }
        }

    // ---- DPP-reduce the 16 j-lanes ----
    #pragma unroll
    for (int ig = 0; ig < 4; ++ig)
        #pragma unroll
        for (int reg = 0; reg < 4; ++reg)
            #pragma unroll
            for (int c = 0; c < 3; ++c) {
                am[ig][reg][c] = red16(am[ig][reg][c]);
                al[ig][reg][c] = red16(al[ig][reg][c]);
            }

    // ---- cross-wave combine via LDS ----
    __shared__ float wacc[4 * 64 * 6];
    if (r16 == 0) {
        #pragma unroll
        for (int ig = 0; ig < 4; ++ig)
            #pragma unroll
            for (int reg = 0; reg < 4; ++reg) {
                const int row = ig * 16 + q * 4 + reg;
                float* p = wacc + (w * 64 + row) * 6;
                p[0] = am[ig][reg][0]; p[1] = am[ig][reg][1]; p[2] = am[ig][reg][2];
                p[3] = al[ig][reg][0]; p[4] = al[ig][reg][1]; p[5] = al[ig][reg][2];
            }
    }
    __syncthreads();
    for (int u = t; u < 384; u += 256) {
        const int row = u / 6, c = u - row * 6;
        const float v = wacc[row * 6 + c] + wacc[(64 + row) * 6 + c] +
                        wacc[(128 + row) * 6 + c] + wacc[(192 + row) * 6 + c];
        partial[((size_t)((js * 8 + b) * NTOK) + i0 + row) * 6 + c] = v;
    }
    if (js == 0 && itb == 0 && t == 0) out[8 * NTOK * 3 + b] = LPCONST;
}

// ---------------- tail ----------------
__device__ __forceinline__ float softplusf(float z) {
    return z > 20.f ? z : log1pf(expf(z));
}

__global__ __launch_bounds__(64) void actor_tail_kernel(
    const float* __restrict__ partial, const float* __restrict__ eps,
    float* __restrict__ out)
{
    const int b = blockIdx.x >> 4;
    const int i = (blockIdx.x & 15) * 64 + threadIdx.x;
    const int gi = b * NTOK + i;

    float am[3] = {}, al[3] = {};
    #pragma unroll
    for (int js = 0; js < 8; ++js) {
        const float* p = partial + (((size_t)js * 8 + b) * NTOK + i) * 6;
        const float2 v0 = *(const float2*)(p);
        const float2 v1 = *(const float2*)(p + 2);
        const float2 v2 = *(const float2*)(p + 4);
        am[0] += v0.x; am[1] += v0.y; am[2] += v1.x;
        al[0] += v1.y; al[1] += v2.x; al[2] += v2.y;
    }

    float lp = 0.f;
    #pragma unroll
    for (int c = 0; c < 3; ++c) {
        const float als = fminf(fmaxf(al[c], -20.f), 2.f);
        const float sd = expf(als);
        const float e = eps[gi * 3 + c];
        const float pre = fmaf(sd, e, am[c]);
        out[gi * 3 + c] = tanhf(pre) * 0.01f;
        const float t2 = 2.f * pre;
        lp += -0.5f * e * e - als - 2.3052328944f + softplusf(t2) + softplusf(-t2);
    }

    #pragma unroll
    for (int m = 1; m < 64; m <<= 1) lp += __shfl_xor(lp, m, 64);
    if (threadIdx.x == 0) atomicAdd(out + NTOK * 8 * 3 + b, lp);
}

extern "C" void kernel_launch(void* const* d_in, const int* in_sizes, int n_in,
                              void* d_out, int out_size, void* d_ws, size_t ws_size,
                              hipStream_t stream) {
    const float* kv = (const float*)d_in[0];
    const float* pos = (const float*)d_in[1];
    const float* eps = (const float*)d_in[2];
    float* out = (float*)d_out;
    float* partial = (float*)d_ws;                                     // 1.5 MiB
    unsigned short* frag = (unsigned short*)((char*)d_ws + (2 << 20)); // 8 MiB

    prepass_kernel<<<dim3(1024), 256, 0, stream>>>(kv, frag);
    actor_gemm_kernel<<<dim3(8, 16, 8), 256, 0, stream>>>(frag, pos, partial, out);
    actor_tail_kernel<<<dim3(128), 64, 0, stream>>>(partial, eps, out);
}